// Round 10
// baseline (578.960 us; speedup 1.0000x reference)
//
#include <hip/hip_runtime.h>
#include <hip/hip_bf16.h>

// ---------- types / helpers ----------
typedef __attribute__((ext_vector_type(4))) float f32x4;
typedef __attribute__((ext_vector_type(8))) short s16x8;

__device__ __forceinline__ unsigned short f2b(float f) {
  unsigned int u = __float_as_uint(f);
  unsigned int r = (u + 0x7FFFu + ((u >> 16) & 1u)) >> 16;   // RNE f32->bf16
  return (unsigned short)r;
}
__device__ __forceinline__ float b2f(unsigned short h) {
  return __uint_as_float(((unsigned int)h) << 16);
}
__device__ __forceinline__ void gload16(const void* g, void* l) {
  __builtin_amdgcn_global_load_lds(
      (const __attribute__((address_space(1))) void*)g,
      (__attribute__((address_space(3))) void*)l, 16, 0, 0);
}

enum { MODE_F32 = 0, MODE_VT = 1, MODE_Y = 2 };
struct OutSpec { void* ptr; int mode; };
struct Outs5 { OutSpec o[5]; };
struct Ptr6 { const float* p[6]; };

// ---------- generic NT MFMA GEMM (R3-proven): used for the y projection ----------
template<int BM, int BN, int WGM, int WGN>
__global__ __launch_bounds__(256) void gemm_nt(
    const unsigned short* __restrict__ A, int lda, long long strideA,
    const unsigned short* __restrict__ Bm, int ldb, long long strideB,
    const float* __restrict__ biasBase, int biasStride, int perZ,
    Outs5 outs, const float* __restrict__ resid, int K)
{
  constexpr int BK = 32;
  constexpr int WM = BM / WGM, WN = BN / WGN;
  constexpr int WR = WM / 16, WC = WN / 16;
  constexpr int CHA = BM * BK / 8;
  constexpr int CHB = BN * BK / 8;
  __shared__ unsigned short lds_a[2][BM * BK];
  __shared__ unsigned short lds_b[2][BN * BK];
  const int z = blockIdx.z;
  const int tid = threadIdx.x;
  const int wave = tid >> 6, lane = tid & 63;
  const int l16 = lane & 15, lhi = lane >> 4;
  const int wm = (wave / WGN) * WM, wn = (wave % WGN) * WN;
  const int m0 = blockIdx.x * BM, n0 = blockIdx.y * BN;
  const unsigned short* Ap = A + (long long)z * strideA;
  const unsigned short* Bp = Bm + (long long)z * strideB;

  auto stage = [&](int buf, int k0) {
#pragma unroll
    for (int p = 0; p < CHA / 256; ++p) {
      int t = p * 256 + tid;
      gload16(Ap + (long long)(m0 + (t >> 2)) * lda + k0 + (t & 3) * 8, &lds_a[buf][t * 8]);
    }
    if constexpr (CHA % 256) {
      if (tid < CHA % 256) {
        int t = (CHA / 256) * 256 + tid;
        gload16(Ap + (long long)(m0 + (t >> 2)) * lda + k0 + (t & 3) * 8, &lds_a[buf][t * 8]);
      }
    }
#pragma unroll
    for (int p = 0; p < CHB / 256; ++p) {
      int t = p * 256 + tid;
      gload16(Bp + (long long)(n0 + (t >> 2)) * ldb + k0 + (t & 3) * 8, &lds_b[buf][t * 8]);
    }
    if constexpr (CHB % 256) {
      if (tid < CHB % 256) {
        int t = (CHB / 256) * 256 + tid;
        gload16(Bp + (long long)(n0 + (t >> 2)) * ldb + k0 + (t & 3) * 8, &lds_b[buf][t * 8]);
      }
    }
  };

  f32x4 acc[WR][WC];
#pragma unroll
  for (int r = 0; r < WR; ++r)
#pragma unroll
    for (int c = 0; c < WC; ++c) { f32x4 zz = {0.f, 0.f, 0.f, 0.f}; acc[r][c] = zz; }

  stage(0, 0);
  __syncthreads();
  int cur = 0;
  for (int k0 = 0; k0 < K; k0 += BK) {
    if (k0 + BK < K) stage(cur ^ 1, k0 + BK);
    s16x8 af[WR], bfv[WC];
#pragma unroll
    for (int r = 0; r < WR; ++r)
      af[r] = *(const s16x8*)&lds_a[cur][(wm + r * 16 + l16) * BK + lhi * 8];
#pragma unroll
    for (int c = 0; c < WC; ++c)
      bfv[c] = *(const s16x8*)&lds_b[cur][(wn + c * 16 + l16) * BK + lhi * 8];
#pragma unroll
    for (int r = 0; r < WR; ++r)
#pragma unroll
      for (int c = 0; c < WC; ++c)
        acc[r][c] = __builtin_amdgcn_mfma_f32_16x16x32_bf16(af[r], bfv[c], acc[r][c], 0, 0, 0);
    __syncthreads();
    cur ^= 1;
  }

  OutSpec spec = perZ ? outs.o[z] : outs.o[0];
  const float* bias = biasBase ? (biasBase + (long long)z * biasStride) : nullptr;
#pragma unroll
  for (int r = 0; r < WR; ++r) {
#pragma unroll
    for (int c = 0; c < WC; ++c) {
      int n = n0 + wn + c * 16 + l16;
      int rb = m0 + wm + r * 16 + lhi * 4;
      float bv = bias ? bias[n] : 0.f;
      float vv[4];
#pragma unroll
      for (int j = 0; j < 4; ++j) vv[j] = acc[r][c][j] + bv;
      if (spec.mode == MODE_F32) {
#pragma unroll
        for (int j = 0; j < 4; ++j)
          ((float*)spec.ptr)[(long long)(rb + j) * 512 + n] = vv[j];
      } else if (spec.mode == MODE_VT) {
        int b = rb >> 9, s = rb & 511;
        ushort4 pk;
        pk.x = f2b(vv[0]); pk.y = f2b(vv[1]); pk.z = f2b(vv[2]); pk.w = f2b(vv[3]);
        *(ushort4*)&((unsigned short*)spec.ptr)[
            (((long long)(b * 8 + (n >> 6))) * 64 + (n & 63)) * 512 + s] = pk;
      } else {                                       // MODE_Y: fp32 y = c + bias + resid
#pragma unroll
        for (int j = 0; j < 4; ++j)
          ((float*)spec.ptr)[(long long)(rb + j) * 512 + n] =
              vv[j] + resid[(long long)(rb + j) * 512 + n];
      }
    }
  }
}

// ---------- mega QKV GEMM with fused quantum gate ----------
// grid (16, 8, 3), 256 thr. z=0: {Q,Cq}->Qext; z=1: {K,Ck}->Kext; z=2: V->Vt.
// BM=128, BN=64, dual-B. Same stage:MFMA ratio as proven 128^2 kernel.
__global__ __launch_bounds__(256) void qkv_fuse(
    const unsigned short* __restrict__ xb, const unsigned short* __restrict__ Wt,
    const float* __restrict__ biasP,
    const float* __restrict__ qp, const float* __restrict__ kp,
    const float* __restrict__ fwq, const float* __restrict__ fwk,
    const unsigned short* __restrict__ mbT,
    unsigned short* __restrict__ Qext, unsigned short* __restrict__ Kext,
    unsigned short* __restrict__ Vt)
{
  __shared__ unsigned short lds[2][8192];   // per buf: A[128*32]@0, B1[64*32]@4096, B2@6144
  const int z = blockIdx.z;
  const int tid = threadIdx.x;
  const int wave = tid >> 6, lane = tid & 63;
  const int l16 = lane & 15, lhi = lane >> 4;
  const int wm = (wave >> 1) * 64, wn = (wave & 1) * 32;
  const int m0 = blockIdx.x * 128, n0 = blockIdx.y * 64;
  const int mat1 = z;                        // Wq/Wk/Wv
  const unsigned short* B1p = Wt + (long long)mat1 * 262144;
  const unsigned short* B2p = Wt + (long long)(z + 3) * 262144;   // qW/kW (z<2)

  auto stage = [&](int buf, int k0) {
#pragma unroll
    for (int p = 0; p < 2; ++p) {
      int t = p * 256 + tid;
      gload16(xb + (long long)(m0 + (t >> 2)) * 512 + k0 + (t & 3) * 8, &lds[buf][t * 8]);
    }
    {
      int row = tid >> 2, cg = tid & 3;
      gload16(B1p + (long long)(n0 + row) * 512 + k0 + cg * 8, &lds[buf][4096 + tid * 8]);
      if (z < 2)
        gload16(B2p + (long long)(n0 + row) * 512 + k0 + cg * 8, &lds[buf][6144 + tid * 8]);
    }
  };

  f32x4 acc1[4][2], acc2[4][2];
#pragma unroll
  for (int r = 0; r < 4; ++r)
#pragma unroll
    for (int c = 0; c < 2; ++c) {
      f32x4 zz = {0.f, 0.f, 0.f, 0.f};
      acc1[r][c] = zz; acc2[r][c] = zz;
    }

  stage(0, 0);
  __syncthreads();
  int cur = 0;
  for (int k0 = 0; k0 < 512; k0 += 32) {
    if (k0 + 32 < 512) stage(cur ^ 1, k0 + 32);
    s16x8 af[4], b1f[2], b2f[2];
#pragma unroll
    for (int r = 0; r < 4; ++r)
      af[r] = *(const s16x8*)&lds[cur][(wm + r * 16 + l16) * 32 + lhi * 8];
#pragma unroll
    for (int c = 0; c < 2; ++c) {
      b1f[c] = *(const s16x8*)&lds[cur][4096 + (wn + c * 16 + l16) * 32 + lhi * 8];
      b2f[c] = *(const s16x8*)&lds[cur][6144 + (wn + c * 16 + l16) * 32 + lhi * 8];
    }
#pragma unroll
    for (int r = 0; r < 4; ++r)
#pragma unroll
      for (int c = 0; c < 2; ++c)
        acc1[r][c] = __builtin_amdgcn_mfma_f32_16x16x32_bf16(af[r], b1f[c], acc1[r][c], 0, 0, 0);
    if (z < 2) {
#pragma unroll
      for (int r = 0; r < 4; ++r)
#pragma unroll
        for (int c = 0; c < 2; ++c)
          acc2[r][c] = __builtin_amdgcn_mfma_f32_16x16x32_bf16(af[r], b2f[c], acc2[r][c], 0, 0, 0);
    }
    __syncthreads();
    cur ^= 1;
  }

  const float* bias1 = biasP + mat1 * 512;
  if (z == 2) {
    // V -> Vt (B,H,HD,S) bf16, 4-row packed stores along s
#pragma unroll
    for (int r = 0; r < 4; ++r)
#pragma unroll
      for (int c = 0; c < 2; ++c) {
        int n = n0 + wn + c * 16 + l16;
        int rb = m0 + wm + r * 16 + lhi * 4;
        float bv = bias1[n];
        int bb = rb >> 9, s = rb & 511;
        ushort4 pk;
        pk.x = f2b(acc1[r][c][0] + bv); pk.y = f2b(acc1[r][c][1] + bv);
        pk.z = f2b(acc1[r][c][2] + bv); pk.w = f2b(acc1[r][c][3] + bv);
        *(ushort4*)&Vt[(((long long)(bb * 8 + (n >> 6))) * 64 + (n & 63)) * 512 + s] = pk;
      }
    return;
  }

  // fuse epilogue (z = 0 Q-side, z = 1 K-side)
  const float* probs = z ? kp : qp;
  const float* fw    = z ? fwk : fwq;
  unsigned short* ext = z ? Kext : Qext;
  const unsigned short* mbs = mbT + z * 16384;
  const float* bias2 = biasP + (z + 3) * 512;
  const float sA = z ? 1.0f : 0.125f;
  const float sB = z ? 1.0f : 0.1f;

  // qout = probs @ mb via one MFMA per tile (probs zero-padded to K=32)
  s16x8 pf[4];
#pragma unroll
  for (int r = 0; r < 4; ++r) {
    s16x8 v = {0, 0, 0, 0, 0, 0, 0, 0};
    if (lhi < 2) {
      const float* pr = probs + (m0 + wm + r * 16 + l16) * 16 + lhi * 8;
#pragma unroll
      for (int e = 0; e < 8; ++e) v[e] = (short)f2b(pr[e]);
    }
    pf[r] = v;
  }
  s16x8 mf[2];
#pragma unroll
  for (int c = 0; c < 2; ++c)
    mf[c] = *(const s16x8*)&mbs[(n0 + wn + c * 16 + l16) * 32 + lhi * 8];
  f32x4 qo[4][2];
#pragma unroll
  for (int r = 0; r < 4; ++r)
#pragma unroll
    for (int c = 0; c < 2; ++c) {
      f32x4 zz = {0.f, 0.f, 0.f, 0.f};
      qo[r][c] = __builtin_amdgcn_mfma_f32_16x16x32_bf16(pf[r], mf[c], zz, 0, 0, 0);
    }

#pragma unroll
  for (int r = 0; r < 4; ++r) {
    int rb = m0 + wm + r * 16 + lhi * 4;
    float fwj[4];
#pragma unroll
    for (int j = 0; j < 4; ++j) fwj[j] = fw[rb + j];
#pragma unroll
    for (int c = 0; c < 2; ++c) {
      int n = n0 + wn + c * 16 + l16;
      float b1 = bias1[n], b2 = bias2[n];
      int h = n >> 6, dd = n & 63;
#pragma unroll
      for (int j = 0; j < 4; ++j) {
        int row = rb + j;
        int bb = row >> 9, ii = row & 511;
        float lin = acc1[r][c][j] + b1;
        float cl  = acc2[r][c][j] + b2;
        float qq = fwj[j] * qo[r][c][j] + (1.f - fwj[j]) * tanhf(cl);
        ext[(((long long)(bb * 8 + h)) * 512 + ii) * 96 + dd] = f2b((0.7f * lin + 0.3f * qq) * sA);
      }
    }
  }

  // interference block [64:80] = sB*probs, [80:96] = 0 (one n-block per side writes it)
  if (blockIdx.y == 0) {
    for (int t = tid; t < 128 * 256; t += 256) {
      int row_l = t >> 8;
      int rem = t & 255;
      int h2 = rem >> 5, e = rem & 31;
      int row = m0 + row_l;
      int bb = row >> 9, ii = row & 511;
      unsigned short v = (e < 16) ? f2b(sB * probs[row * 16 + e]) : (unsigned short)0;
      ext[(((long long)(bb * 8 + h2)) * 512 + ii) * 96 + 64 + e] = v;
    }
  }
}

// ---------- fused attention (R3 structure, proven) ----------
__global__ __launch_bounds__(256, 1) void fused_attn(
    const unsigned short* __restrict__ Qe, const unsigned short* __restrict__ Ke,
    const unsigned short* __restrict__ Vt, float* __restrict__ attn,
    unsigned short* __restrict__ ctx)
{
  __shared__ unsigned short lds[55296];   // 110.6 KB
  const int z = blockIdx.x, rb = blockIdx.y;
  const int m0 = rb * 64;
  const int b = z >> 3, h = z & 7;
  const int tid = threadIdx.x;
  const int w = tid >> 6, lane = tid & 63;
  const int l16 = lane & 15, lhi = lane >> 4;
  const int rx3 = l16 & 3, rx7 = l16 & 7;

#pragma unroll
  for (int p = 0; p < 3; ++p) {
    int t = p * 256 + tid;
    int row = t / 12, c = t % 12;
    gload16(Qe + ((long long)(z * 512 + m0 + row)) * 96 + (c ^ (row & 3)) * 8, &lds[t * 8]);
  }
#pragma unroll
  for (int p = 0; p < 24; ++p) {
    int t = p * 256 + tid;
    int row = t / 12, c = t % 12;
    gload16(Ke + ((long long)(z * 512 + row)) * 96 + (c ^ (row & 3)) * 8, &lds[6144 + t * 8]);
  }
  __syncthreads();

  const unsigned short* Qs = lds;
  const unsigned short* Ks = lds + 6144;
  s16x8 aq[3];
#pragma unroll
  for (int kk = 0; kk < 3; ++kk)
    aq[kk] = *(const s16x8*)&Qs[(w * 16 + l16) * 96 + (kk * 4 + (lhi ^ rx3)) * 8];
  f32x4 acc[32];
#pragma unroll
  for (int c = 0; c < 32; ++c) { f32x4 zz = {0.f, 0.f, 0.f, 0.f}; acc[c] = zz; }
#pragma unroll
  for (int c = 0; c < 32; ++c) {
#pragma unroll
    for (int kk = 0; kk < 3; ++kk) {
      s16x8 bf = *(const s16x8*)&Ks[(c * 16 + l16) * 96 + (kk * 4 + (lhi ^ rx3)) * 8];
      acc[c] = __builtin_amdgcn_mfma_f32_16x16x32_bf16(aq[kk], bf, acc[c], 0, 0, 0);
    }
  }

  float inv[4];
#pragma unroll
  for (int j = 0; j < 4; ++j) {
    float mx = acc[0][j];
#pragma unroll
    for (int c = 1; c < 32; ++c) mx = fmaxf(mx, acc[c][j]);
    mx = fmaxf(mx, __shfl_xor(mx, 1));
    mx = fmaxf(mx, __shfl_xor(mx, 2));
    mx = fmaxf(mx, __shfl_xor(mx, 4));
    mx = fmaxf(mx, __shfl_xor(mx, 8));
    float sum = 0.f;
#pragma unroll
    for (int c = 0; c < 32; ++c) { float e = __expf(acc[c][j] - mx); acc[c][j] = e; sum += e; }
    sum += __shfl_xor(sum, 1);
    sum += __shfl_xor(sum, 2);
    sum += __shfl_xor(sum, 4);
    sum += __shfl_xor(sum, 8);
    inv[j] = 1.f / sum;
  }
  __syncthreads();

#pragma unroll
  for (int p = 0; p < 8; ++p) {
    int t = p * 256 + tid;
    int row = t >> 5, c = t & 31;
    gload16(Vt + (long long)z * 32768 + row * 512 + (c ^ (row & 7)) * 8, &lds[32768 + t * 8]);
  }
  unsigned short* S = lds;
  {
    float* ap = attn + (long long)z * 262144;
#pragma unroll
    for (int j = 0; j < 4; ++j) {
      int row_l = w * 16 + lhi * 4 + j;
      int rs = row_l & 7;
      float* arow = ap + (long long)(m0 + row_l) * 512;
      unsigned short* srow = S + row_l * 512;
#pragma unroll
      for (int c = 0; c < 32; ++c) {
        float p = acc[c][j] * inv[j];
        int col = c * 16 + l16;
        arow[col] = p;
        srow[((col >> 3) ^ rs) * 8 + (col & 7)] = f2b(p);
      }
    }
  }
  __syncthreads();

  const unsigned short* Vl = lds + 32768;
  f32x4 acc2[4];
#pragma unroll
  for (int c2 = 0; c2 < 4; ++c2) { f32x4 zz = {0.f, 0.f, 0.f, 0.f}; acc2[c2] = zz; }
  const int qrow = w * 16 + l16;
#pragma unroll
  for (int kk = 0; kk < 8; ++kk) {
    s16x8 a = *(const s16x8*)&S[qrow * 512 + ((kk * 4 + lhi) ^ rx7) * 8];
#pragma unroll
    for (int c2 = 0; c2 < 4; ++c2) {
      s16x8 bf = *(const s16x8*)&Vl[(c2 * 16 + l16) * 256 + ((kk * 4 + lhi) ^ rx7) * 8];
      acc2[c2] = __builtin_amdgcn_mfma_f32_16x16x32_bf16(a, bf, acc2[c2], 0, 0, 0);
    }
  }
  __syncthreads();
#pragma unroll
  for (int p = 0; p < 8; ++p) {
    int t = p * 256 + tid;
    int row = t >> 5, c = t & 31;
    gload16(Vt + (long long)z * 32768 + row * 512 + 256 + (c ^ (row & 7)) * 8,
            &lds[32768 + t * 8]);
  }
  __syncthreads();
#pragma unroll
  for (int kk = 8; kk < 16; ++kk) {
    s16x8 a = *(const s16x8*)&S[qrow * 512 + ((kk * 4 + lhi) ^ rx7) * 8];
#pragma unroll
    for (int c2 = 0; c2 < 4; ++c2) {
      s16x8 bf = *(const s16x8*)&Vl[(c2 * 16 + l16) * 256 + (((kk - 8) * 4 + lhi) ^ rx7) * 8];
      acc2[c2] = __builtin_amdgcn_mfma_f32_16x16x32_bf16(a, bf, acc2[c2], 0, 0, 0);
    }
  }
#pragma unroll
  for (int c2 = 0; c2 < 4; ++c2) {
#pragma unroll
    for (int j = 0; j < 4; ++j) {
      int row_g = m0 + w * 16 + lhi * 4 + j;
      ctx[((long long)(b * 512 + row_g)) * 512 + h * 64 + c2 * 16 + l16] = f2b(acc2[c2][j]);
    }
  }
}

// ---------- weight transpose ----------
__global__ __launch_bounds__(256) void wt_k(Ptr6 srcs, unsigned short* __restrict__ wt) {
  __shared__ float tile[32][33];
  int zz = blockIdx.z;
  int l = zz / 6, mat = zz % 6;
  const float* src = srcs.p[mat] + (long long)l * 262144;
  int tx = threadIdx.x, ty = threadIdx.y;
  int n0 = blockIdx.x * 32, k0 = blockIdx.y * 32;
#pragma unroll
  for (int r = 0; r < 4; ++r)
    tile[ty + r * 8][tx] = src[(long long)(k0 + ty + r * 8) * 512 + n0 + tx];
  __syncthreads();
#pragma unroll
  for (int r = 0; r < 4; ++r)
    wt[(long long)zz * 262144 + (long long)(n0 + ty + r * 8) * 512 + k0 + tx] =
        f2b(tile[tx][ty + r * 8]);
}

// ---------- bias packing + fused quantum matrices + mbT ----------
__global__ __launch_bounds__(256) void prep_k(Ptr6 biases,
    const float* __restrict__ qwr, const float* __restrict__ qwi, const float* __restrict__ qem,
    const float* __restrict__ kwr, const float* __restrict__ kwi, const float* __restrict__ kem,
    const float* __restrict__ qmb, const float* __restrict__ kmb,
    float* __restrict__ biasPacked, float* __restrict__ ArAi,
    unsigned short* __restrict__ mbT) {
  int l = blockIdx.x, t = threadIdx.x;
  for (int m = 0; m < 6; ++m)
    for (int d = t; d < 512; d += 256)
      biasPacked[(l * 6 + m) * 512 + d] = biases.p[m][l * 512 + d];
  int i = t >> 4, j = t & 15;
  const float* em0 = qem + l * 256;
  float ar = 0.f, ai = 0.f;
  for (int tt = 0; tt < 16; ++tt) {
    ar += qwr[l * 256 + i * 16 + tt] * em0[tt * 16 + j];
    ai += qwi[l * 256 + i * 16 + tt] * em0[tt * 16 + j];
  }
  ArAi[(l * 4 + 0) * 256 + t] = ar;
  ArAi[(l * 4 + 1) * 256 + t] = ai;
  const float* em1 = kem + l * 256;
  ar = 0.f; ai = 0.f;
  for (int tt = 0; tt < 16; ++tt) {
    ar += kwr[l * 256 + i * 16 + tt] * em1[tt * 16 + j];
    ai += kwi[l * 256 + i * 16 + tt] * em1[tt * 16 + j];
  }
  ArAi[(l * 4 + 2) * 256 + t] = ar;
  ArAi[(l * 4 + 3) * 256 + t] = ai;
  // mbT[side][n][32]: mbT[n][k] = mb[k][n] (k<16), 0 (k>=16)
  for (int n = t; n < 512; n += 256) {
#pragma unroll
    for (int k = 0; k < 16; ++k) {
      mbT[(long long)(l * 2 + 0) * 16384 + n * 32 + k] = f2b(qmb[l * 8192 + k * 512 + n]);
      mbT[(long long)(l * 2 + 1) * 16384 + n * 32 + k] = f2b(kmb[l * 8192 + k * 512 + n]);
    }
#pragma unroll
    for (int k = 16; k < 32; ++k) {
      mbT[(long long)(l * 2 + 0) * 16384 + n * 32 + k] = 0;
      mbT[(long long)(l * 2 + 1) * 16384 + n * 32 + k] = 0;
    }
  }
}

// ---------- visual projection ----------
__global__ __launch_bounds__(512) void vispart_k(const float* __restrict__ vis,
    const float* __restrict__ Wvis, float* __restrict__ part) {
  int b = blockIdx.x, chunk = blockIdx.y, d = threadIdx.x;
  float acc = 0.f;
  for (int k = chunk * 64; k < chunk * 64 + 64; ++k)
    acc += vis[b * 2048 + k] * Wvis[(long long)k * 512 + d];
  part[(b * 32 + chunk) * 512 + d] = acc;
}
__global__ __launch_bounds__(512) void projsum_k(const float* __restrict__ part,
    const float* __restrict__ bvis, const float* __restrict__ temporal,
    const float* __restrict__ Wtemp, const float* __restrict__ btemp, float* __restrict__ proj) {
  int b = blockIdx.x, d = threadIdx.x;
  float acc = bvis[d] + btemp[d];
  for (int c = 0; c < 32; ++c) acc += part[(b * 32 + c) * 512 + d];
  for (int k = 0; k < 64; ++k) acc += temporal[b * 64 + k] * Wtemp[k * 512 + d];
  proj[b * 512 + d] = acc;
}

// ---------- embedding + positional encoding ----------
__global__ __launch_bounds__(512) void embed_k(const int* __restrict__ text,
    const float* __restrict__ emb, const float* __restrict__ proj,
    float* __restrict__ x, unsigned short* __restrict__ xb) {
  int row = blockIdx.x;
  int b = row >> 9, s = row & 511;
  int d = threadIdx.x;
  int tok = text[row];
  float v = emb[(long long)tok * 512 + d] + proj[b * 512 + d];
  float fr = __expf((float)((d >> 1) << 1) * (-9.2103403719761836f / 512.f));
  float ang = (float)s * fr;
  v += (d & 1) ? cosf(ang) : sinf(ang);
  x[(long long)row * 512 + d] = v;
  xb[(long long)row * 512 + d] = f2b(v);
}

// ---------- quantum branch (fp32 x input, R3) ----------
__global__ __launch_bounds__(64) void quantum_k(const float* __restrict__ x,
    const float* __restrict__ sg_q, const float* __restrict__ sg_k,
    const float* __restrict__ ArAiL, float* __restrict__ qp, float* __restrict__ kp,
    float* __restrict__ fwq, float* __restrict__ fwk) {
  int row = blockIdx.x, side = blockIdx.y, lane = threadIdx.x;
  const float* sg = side ? sg_k : sg_q;
  const float* Ar = ArAiL + side * 512;
  const float* Ai = Ar + 256;
  float acc[16];
#pragma unroll
  for (int j = 0; j < 16; ++j) acc[j] = 0.f;
  const float* xr = x + (long long)row * 512;
#pragma unroll
  for (int kk = 0; kk < 8; ++kk) {
    float xv = xr[kk * 64 + lane];
    const float* sgr = sg + (kk * 64 + lane) * 16;
#pragma unroll
    for (int j = 0; j < 16; ++j) acc[j] += xv * sgr[j];
  }
#pragma unroll
  for (int s = 32; s; s >>= 1)
#pragma unroll
    for (int j = 0; j < 16; ++j) acc[j] += __shfl_xor(acc[j], s);
  int j = lane & 15;
  float tr = 0.f, ti = 0.f;
#pragma unroll
  for (int t = 0; t < 16; ++t) {
    tr += acc[t] * Ar[t * 16 + j];
    ti += acc[t] * Ai[t * 16 + j];
  }
  float p = tr * tr + ti * ti;
  float ps = p;
#pragma unroll
  for (int s = 1; s < 16; s <<= 1) ps += __shfl_xor(ps, s);
  if (lane < 16) (side ? kp : qp)[row * 16 + lane] = p;
  if (lane == 0) (side ? fwk : fwq)[row] = 1.f / (1.f + __expf(-ps * (1.f / 16.f)));
}

// ---------- wave-per-row layernorm (fp32 y input, R3) ----------
__global__ __launch_bounds__(256) void ln_k(const float* __restrict__ y,
    const float* __restrict__ g, const float* __restrict__ be,
    float* __restrict__ xo, unsigned short* __restrict__ xb, float* __restrict__ xo2) {
  int wv = threadIdx.x >> 6, lane = threadIdx.x & 63;
  long long row = (long long)blockIdx.x * 4 + wv;
  const float* yr = y + row * 512 + lane * 8;
  f32x4 a = *(const f32x4*)yr, b = *(const f32x4*)(yr + 4);
  float s = a[0] + a[1] + a[2] + a[3] + b[0] + b[1] + b[2] + b[3];
#pragma unroll
  for (int m = 32; m; m >>= 1) s += __shfl_xor(s, m);
  float mu = s * (1.f / 512.f);
  float d[8], vs = 0.f;
#pragma unroll
  for (int j = 0; j < 4; ++j) { d[j] = a[j] - mu; vs += d[j] * d[j]; }
#pragma unroll
  for (int j = 0; j < 4; ++j) { d[4 + j] = b[j] - mu; vs += d[4 + j] * d[4 + j]; }
#pragma unroll
  for (int m = 32; m; m >>= 1) vs += __shfl_xor(vs, m);
  float rstd = rsqrtf(vs * (1.f / 512.f) + 1e-5f);
  f32x4 g0 = *(const f32x4*)(g + lane * 8), g1 = *(const f32x4*)(g + lane * 8 + 4);
  f32x4 b0 = *(const f32x4*)(be + lane * 8), b1 = *(const f32x4*)(be + lane * 8 + 4);
  f32x4 o0, o1; s16x8 ob;
#pragma unroll
  for (int j = 0; j < 4; ++j) { o0[j] = d[j] * rstd * g0[j] + b0[j]; ob[j] = (short)f2b(o0[j]); }
#pragma unroll
  for (int j = 0; j < 4; ++j) { o1[j] = d[4 + j] * rstd * g1[j] + b1[j]; ob[4 + j] = (short)f2b(o1[j]); }
  float* xr = xo + row * 512 + lane * 8;
  *(f32x4*)xr = o0; *(f32x4*)(xr + 4) = o1;
  *(s16x8*)(xb + row * 512 + lane * 8) = ob;
  if (xo2) {
    float* x2 = xo2 + row * 512 + lane * 8;
    *(f32x4*)x2 = o0; *(f32x4*)(x2 + 4) = o1;
  }
}

// ---------- pooled heads ----------
__global__ __launch_bounds__(512) void poolpart_k(const float* __restrict__ x,
                                                   float* __restrict__ part) {
  int b = blockIdx.x, ch = blockIdx.y, d = threadIdx.x;
  float s = 0.f;
  for (int r = 0; r < 64; ++r) s += x[((long long)(b * 512 + ch * 64 + r)) * 512 + d];
  part[(b * 8 + ch) * 512 + d] = s;
}
__global__ __launch_bounds__(512) void head_k(const float* __restrict__ part,
    const float* __restrict__ Ws, const float* __restrict__ bs,
    const float* __restrict__ Wd, const float* __restrict__ bd,
    const float* __restrict__ We, const float* __restrict__ be, float* __restrict__ out) {
  __shared__ float pooled[512];
  __shared__ float dl[5];
  int b = blockIdx.x, d = threadIdx.x;
  float s = 0.f;
  for (int t = 0; t < 8; ++t) s += part[(b * 8 + t) * 512 + d];
  pooled[d] = s * (1.f / 512.f);
  __syncthreads();
  {
    int o = d >> 3, sub = d & 7;
    float a = 0.f;
    for (int t = sub; t < 512; t += 8) a += pooled[t] * Ws[t * 64 + o];
    a += __shfl_xor(a, 1); a += __shfl_xor(a, 2); a += __shfl_xor(a, 4);
    if (sub == 0) out[b * 64 + o] = 1.f / (1.f + __expf(-(a + bs[o])));
  }
  if (d < 40) {
    int o = d >> 3, sub = d & 7;
    float a = 0.f;
    for (int t = sub; t < 512; t += 8) a += pooled[t] * Wd[t * 5 + o];
    a += __shfl_xor(a, 1); a += __shfl_xor(a, 2); a += __shfl_xor(a, 4);
    if (sub == 0) dl[o] = a + bd[o];
  } else if (d >= 64 && d < 72) {
    int sub = d & 7;
    float a = 0.f;
    for (int t = sub; t < 512; t += 8) a += pooled[t] * We[t];
    a += __shfl_xor(a, 1); a += __shfl_xor(a, 2); a += __shfl_xor(a, 4);
    if (sub == 0) out[276 + b] = 1.f / (1.f + __expf(-(a + be[0])));
  }
  __syncthreads();
  if (d < 5) {
    float mx = dl[0];
    for (int j = 1; j < 5; ++j) mx = fmaxf(mx, dl[j]);
    float sm = 0.f;
    for (int j = 0; j < 5; ++j) sm += __expf(dl[j] - mx);
    out[256 + b * 5 + d] = __expf(dl[d] - mx) / sm;
  }
}

// ---------- host ----------
extern "C" void kernel_launch(void* const* d_in, const int* in_sizes, int n_in,
                              void* d_out, int out_size, void* d_ws, size_t ws_size,
                              hipStream_t stream) {
  (void)in_sizes; (void)n_in; (void)out_size; (void)ws_size;
  const int*   text     = (const int*)  d_in[0];
  const float* visual   = (const float*)d_in[1];
  const float* temporal = (const float*)d_in[2];
  const float* embedw   = (const float*)d_in[3];
  const float* Wvis  = (const float*)d_in[4];  const float* bvis  = (const float*)d_in[5];
  const float* Wtemp = (const float*)d_in[6];  const float* btemp = (const float*)d_in[7];
  const float* Wq = (const float*)d_in[8];   const float* bq = (const float*)d_in[9];
  const float* Wk = (const float*)d_in[10];  const float* bk = (const float*)d_in[11];
  const float* Wv = (const float*)d_in[12];  const float* bv = (const float*)d_in[13];
  const float* Wo = (const float*)d_in[14];  const float* bo = (const float*)d_in[15];
  const float* qW = (const float*)d_in[16];  const float* qb = (const float*)d_in[17];
  const float* q_qwr = (const float*)d_in[18]; const float* q_qwi = (const float*)d_in[19];
  const float* q_sg  = (const float*)d_in[20]; const float* q_em  = (const float*)d_in[21];
  const float* q_mb  = (const float*)d_in[22];
  const float* kW = (const float*)d_in[23];  const float* kb = (const float*)d_in[24];
  const float* k_qwr = (const float*)d_in[25]; const float* k_qwi = (const float*)d_in[26];
  const float* k_sg  = (const float*)d_in[27]; const float* k_em  = (const float*)d_in[28];
  const float* k_mb  = (const float*)d_in[29];
  const float* ln_g = (const float*)d_in[30]; const float* ln_b = (const float*)d_in[31];
  const float* Ws = (const float*)d_in[32];  const float* bs_ = (const float*)d_in[33];
  const float* Wd = (const float*)d_in[34];  const float* bd = (const float*)d_in[35];
  const float* We = (const float*)d_in[36];  const float* be = (const float*)d_in[37];
  float* out = (float*)d_out;

  char* w = (char*)d_ws;
  auto alloc = [&](size_t bytes) {
    char* p = w;
    w += (bytes + 255) & ~(size_t)255;
    return p;
  };
  float* ws_x   = (float*)alloc(2048ll * 512 * 4);
  unsigned short* ws_xb = (unsigned short*)alloc(2048ll * 512 * 2);
  unsigned short* ws_Wt = (unsigned short*)alloc(36ll * 262144 * 2);
  float* ws_bias = (float*)alloc(6ll * 6 * 512 * 4);
  float* ws_ArAi = (float*)alloc(6ll * 1024 * 4);
  unsigned short* ws_mbT = (unsigned short*)alloc(12ll * 16384 * 2);
  float* ws_proj = (float*)alloc(4ll * 512 * 4);
  float* ws_vp   = (float*)alloc(4ll * 32 * 512 * 4);
  float* ws_qp   = (float*)alloc(2048ll * 16 * 4);
  float* ws_kp   = (float*)alloc(2048ll * 16 * 4);
  float* ws_fwq  = (float*)alloc(2048ll * 4);
  float* ws_fwk  = (float*)alloc(2048ll * 4);
  unsigned short* ws_Vt   = (unsigned short*)alloc(2048ll * 512 * 2);
  unsigned short* ws_Qext = (unsigned short*)alloc(4ll * 8 * 512 * 96 * 2);
  unsigned short* ws_Kext = (unsigned short*)alloc(4ll * 8 * 512 * 96 * 2);
  unsigned short* ws_ctx  = (unsigned short*)alloc(2048ll * 512 * 2);
  float* ws_y    = (float*)alloc(2048ll * 512 * 4);

  Ptr6 wsrc = {{Wq, Wk, Wv, qW, kW, Wo}};
  wt_k<<<dim3(16, 16, 36), dim3(32, 8), 0, stream>>>(wsrc, ws_Wt);
  Ptr6 bsrc = {{bq, bk, bv, qb, kb, bo}};
  prep_k<<<dim3(6), dim3(256), 0, stream>>>(bsrc, q_qwr, q_qwi, q_em, k_qwr, k_qwi, k_em,
                                            q_mb, k_mb, ws_bias, ws_ArAi, ws_mbT);
  vispart_k<<<dim3(4, 32), dim3(512), 0, stream>>>(visual, Wvis, ws_vp);
  projsum_k<<<dim3(4), dim3(512), 0, stream>>>(ws_vp, bvis, temporal, Wtemp, btemp, ws_proj);
  embed_k<<<dim3(2048), dim3(512), 0, stream>>>(text, embedw, ws_proj, ws_x, ws_xb);

  const long long ATTN_OFF = 280ll + 1048576ll;
  for (int l = 0; l < 6; ++l) {
    const unsigned short* WtL = ws_Wt + (long long)l * 6 * 262144;
    const float* biasL = ws_bias + (long long)l * 6 * 512;

    quantum_k<<<dim3(2048, 2), 64, 0, stream>>>(ws_x, q_sg + l * 8192, k_sg + l * 8192,
        ws_ArAi + l * 1024, ws_qp, ws_kp, ws_fwq, ws_fwk);

    qkv_fuse<<<dim3(16, 8, 3), 256, 0, stream>>>(
        ws_xb, WtL, biasL, ws_qp, ws_kp, ws_fwq, ws_fwk,
        ws_mbT + (long long)l * 32768, ws_Qext, ws_Kext, ws_Vt);

    fused_attn<<<dim3(32, 8), 256, 0, stream>>>(
        ws_Qext, ws_Kext, ws_Vt, out + ATTN_OFF + (long long)l * 8388608, ws_ctx);

    Outs5 oy{};
    oy.o[0] = { ws_y, MODE_Y };
    gemm_nt<64, 64, 2, 2><<<dim3(32, 8, 1), 256, 0, stream>>>(
        ws_ctx, 512, 0ll, WtL + 5 * 262144, 512, 0ll, biasL + 5 * 512, 0, 0, oy, ws_x, 512);

    ln_k<<<dim3(512), dim3(256), 0, stream>>>(ws_y, ln_g + l * 512, ln_b + l * 512,
        ws_x, ws_xb, (l == 5) ? (out + 280) : nullptr);
  }

  poolpart_k<<<dim3(4, 8), dim3(512), 0, stream>>>(ws_x, ws_vp);
  head_k<<<dim3(4), dim3(512), 0, stream>>>(ws_vp, Ws, bs_, Wd, bd, We, be, out);
}

// Round 11
// 503.363 us; speedup vs baseline: 1.1502x; 1.1502x over previous
//
#include <hip/hip_runtime.h>
#include <hip/hip_bf16.h>

// ---------- types / helpers ----------
typedef __attribute__((ext_vector_type(4))) float f32x4;
typedef __attribute__((ext_vector_type(8))) short s16x8;

__device__ __forceinline__ unsigned short f2b(float f) {
  unsigned int u = __float_as_uint(f);
  unsigned int r = (u + 0x7FFFu + ((u >> 16) & 1u)) >> 16;   // RNE f32->bf16
  return (unsigned short)r;
}
__device__ __forceinline__ float b2f(unsigned short h) {
  return __uint_as_float(((unsigned int)h) << 16);
}
__device__ __forceinline__ void gload16(const void* g, void* l) {
  __builtin_amdgcn_global_load_lds(
      (const __attribute__((address_space(1))) void*)g,
      (__attribute__((address_space(3))) void*)l, 16, 0, 0);
}

enum { MODE_F32 = 0, MODE_VT = 1, MODE_Y = 2 };
struct OutSpec { void* ptr; int mode; };
struct Outs5 { OutSpec o[5]; };
struct Ptr6 { const float* p[6]; };

// ---------- generic NT MFMA GEMM: C[m][n] = sum_k A[m][k]*B[n][k] (+bias)(+resid) ----------
template<int BM, int BN, int WGM, int WGN>
__global__ __launch_bounds__(256) void gemm_nt(
    const unsigned short* __restrict__ A, int lda, long long strideA,
    const unsigned short* __restrict__ Bm, int ldb, long long strideB,
    const float* __restrict__ biasBase, int biasStride, int perZ,
    Outs5 outs, const float* __restrict__ resid, int K)
{
  constexpr int BK = 32;
  constexpr int WM = BM / WGM, WN = BN / WGN;
  constexpr int WR = WM / 16, WC = WN / 16;
  constexpr int CHA = BM * BK / 8;
  constexpr int CHB = BN * BK / 8;
  __shared__ unsigned short lds_a[2][BM * BK];
  __shared__ unsigned short lds_b[2][BN * BK];
  const int z = blockIdx.z;
  const int tid = threadIdx.x;
  const int wave = tid >> 6, lane = tid & 63;
  const int l16 = lane & 15, lhi = lane >> 4;
  const int wm = (wave / WGN) * WM, wn = (wave % WGN) * WN;
  const int m0 = blockIdx.x * BM, n0 = blockIdx.y * BN;
  const unsigned short* Ap = A + (long long)z * strideA;
  const unsigned short* Bp = Bm + (long long)z * strideB;

  auto stage = [&](int buf, int k0) {
#pragma unroll
    for (int p = 0; p < CHA / 256; ++p) {
      int t = p * 256 + tid;
      gload16(Ap + (long long)(m0 + (t >> 2)) * lda + k0 + (t & 3) * 8, &lds_a[buf][t * 8]);
    }
    if constexpr (CHA % 256) {
      if (tid < CHA % 256) {
        int t = (CHA / 256) * 256 + tid;
        gload16(Ap + (long long)(m0 + (t >> 2)) * lda + k0 + (t & 3) * 8, &lds_a[buf][t * 8]);
      }
    }
#pragma unroll
    for (int p = 0; p < CHB / 256; ++p) {
      int t = p * 256 + tid;
      gload16(Bp + (long long)(n0 + (t >> 2)) * ldb + k0 + (t & 3) * 8, &lds_b[buf][t * 8]);
    }
    if constexpr (CHB % 256) {
      if (tid < CHB % 256) {
        int t = (CHB / 256) * 256 + tid;
        gload16(Bp + (long long)(n0 + (t >> 2)) * ldb + k0 + (t & 3) * 8, &lds_b[buf][t * 8]);
      }
    }
  };

  f32x4 acc[WR][WC];
#pragma unroll
  for (int r = 0; r < WR; ++r)
#pragma unroll
    for (int c = 0; c < WC; ++c) { f32x4 zz = {0.f, 0.f, 0.f, 0.f}; acc[r][c] = zz; }

  stage(0, 0);
  __syncthreads();
  int cur = 0;
  for (int k0 = 0; k0 < K; k0 += BK) {
    if (k0 + BK < K) stage(cur ^ 1, k0 + BK);
    s16x8 af[WR], bfv[WC];
#pragma unroll
    for (int r = 0; r < WR; ++r)
      af[r] = *(const s16x8*)&lds_a[cur][(wm + r * 16 + l16) * BK + lhi * 8];
#pragma unroll
    for (int c = 0; c < WC; ++c)
      bfv[c] = *(const s16x8*)&lds_b[cur][(wn + c * 16 + l16) * BK + lhi * 8];
#pragma unroll
    for (int r = 0; r < WR; ++r)
#pragma unroll
      for (int c = 0; c < WC; ++c)
        acc[r][c] = __builtin_amdgcn_mfma_f32_16x16x32_bf16(af[r], bfv[c], acc[r][c], 0, 0, 0);
    __syncthreads();
    cur ^= 1;
  }

  OutSpec spec = perZ ? outs.o[z] : outs.o[0];
  const float* bias = biasBase ? (biasBase + (long long)z * biasStride) : nullptr;
#pragma unroll
  for (int r = 0; r < WR; ++r) {
#pragma unroll
    for (int c = 0; c < WC; ++c) {
      int n = n0 + wn + c * 16 + l16;
      int rb = m0 + wm + r * 16 + lhi * 4;
      float bv = bias ? bias[n] : 0.f;
      float vv[4];
#pragma unroll
      for (int j = 0; j < 4; ++j) vv[j] = acc[r][c][j] + bv;
      if (spec.mode == MODE_F32) {
#pragma unroll
        for (int j = 0; j < 4; ++j)
          ((float*)spec.ptr)[(long long)(rb + j) * 512 + n] = vv[j];
      } else if (spec.mode == MODE_VT) {             // V^T: (B,H,HD,S) bf16
        int b = rb >> 9, s = rb & 511;
        ushort4 pk;
        pk.x = f2b(vv[0]); pk.y = f2b(vv[1]); pk.z = f2b(vv[2]); pk.w = f2b(vv[3]);
        *(ushort4*)&((unsigned short*)spec.ptr)[
            (((long long)(b * 8 + (n >> 6))) * 64 + (n & 63)) * 512 + s] = pk;
      } else {                                       // MODE_Y: y = c + bias + resid
#pragma unroll
        for (int j = 0; j < 4; ++j)
          ((float*)spec.ptr)[(long long)(rb + j) * 512 + n] =
              vv[j] + resid[(long long)(rb + j) * 512 + n];
      }
    }
  }
}

// ---------- fused attention: scores -> softmax -> attn(fp32 out) -> PV -> ctx ----------
// grid (32 z, 8 rb), 256 thr. Qe/Ke: (z,s,96) bf16; Vt: (z,hd,s) bf16.
// LDS phase1: Q[64][96] @0, K[512][96] @6144 (shorts). Phase2: S[64][512] @0, V[64][256] @32768.
__global__ __launch_bounds__(256, 1) void fused_attn(
    const unsigned short* __restrict__ Qe, const unsigned short* __restrict__ Ke,
    const unsigned short* __restrict__ Vt, float* __restrict__ attn,
    unsigned short* __restrict__ ctx)
{
  __shared__ unsigned short lds[55296];   // 110.6 KB
  const int z = blockIdx.x, rb = blockIdx.y;
  const int m0 = rb * 64;
  const int b = z >> 3, h = z & 7;
  const int tid = threadIdx.x;
  const int w = tid >> 6, lane = tid & 63;
  const int l16 = lane & 15, lhi = lane >> 4;
  const int rx3 = l16 & 3, rx7 = l16 & 7;

  // ---- stage Q (768 chunks) + K (6144 chunks), pre-swizzled source ----
#pragma unroll
  for (int p = 0; p < 3; ++p) {
    int t = p * 256 + tid;
    int row = t / 12, c = t % 12;
    gload16(Qe + ((long long)(z * 512 + m0 + row)) * 96 + (c ^ (row & 3)) * 8, &lds[t * 8]);
  }
#pragma unroll
  for (int p = 0; p < 24; ++p) {
    int t = p * 256 + tid;
    int row = t / 12, c = t % 12;
    gload16(Ke + ((long long)(z * 512 + row)) * 96 + (c ^ (row & 3)) * 8, &lds[6144 + t * 8]);
  }
  __syncthreads();

  // ---- scores: wave w owns rows m0+16w..+15, all 512 kv cols ----
  const unsigned short* Qs = lds;
  const unsigned short* Ks = lds + 6144;
  s16x8 aq[3];
#pragma unroll
  for (int kk = 0; kk < 3; ++kk)
    aq[kk] = *(const s16x8*)&Qs[(w * 16 + l16) * 96 + (kk * 4 + (lhi ^ rx3)) * 8];
  f32x4 acc[32];
#pragma unroll
  for (int c = 0; c < 32; ++c) { f32x4 zz = {0.f, 0.f, 0.f, 0.f}; acc[c] = zz; }
#pragma unroll
  for (int c = 0; c < 32; ++c) {
#pragma unroll
    for (int kk = 0; kk < 3; ++kk) {
      s16x8 bf = *(const s16x8*)&Ks[(c * 16 + l16) * 96 + (kk * 4 + (lhi ^ rx3)) * 8];
      acc[c] = __builtin_amdgcn_mfma_f32_16x16x32_bf16(aq[kk], bf, acc[c], 0, 0, 0);
    }
  }

  // ---- softmax stats in-register (rows = lhi*4+j, cols spread over l16 + frag) ----
  float inv[4];
#pragma unroll
  for (int j = 0; j < 4; ++j) {
    float mx = acc[0][j];
#pragma unroll
    for (int c = 1; c < 32; ++c) mx = fmaxf(mx, acc[c][j]);
    mx = fmaxf(mx, __shfl_xor(mx, 1));
    mx = fmaxf(mx, __shfl_xor(mx, 2));
    mx = fmaxf(mx, __shfl_xor(mx, 4));
    mx = fmaxf(mx, __shfl_xor(mx, 8));
    float sum = 0.f;
#pragma unroll
    for (int c = 0; c < 32; ++c) { float e = __expf(acc[c][j] - mx); acc[c][j] = e; sum += e; }
    sum += __shfl_xor(sum, 1);
    sum += __shfl_xor(sum, 2);
    sum += __shfl_xor(sum, 4);
    sum += __shfl_xor(sum, 8);
    inv[j] = 1.f / sum;
  }
  __syncthreads();                       // all waves done reading Q/K LDS

  // ---- stage V half 0 (64 rows x 256 kv), overlaps with S/attn writes ----
#pragma unroll
  for (int p = 0; p < 8; ++p) {
    int t = p * 256 + tid;
    int row = t >> 5, c = t & 31;
    gload16(Vt + (long long)z * 32768 + row * 512 + (c ^ (row & 7)) * 8, &lds[32768 + t * 8]);
  }
  // ---- write attn fp32 (d_out) + normalized bf16 P into S LDS ----
  unsigned short* S = lds;
  {
    float* ap = attn + (long long)z * 262144;
#pragma unroll
    for (int j = 0; j < 4; ++j) {
      int row_l = w * 16 + lhi * 4 + j;
      int rs = row_l & 7;
      float* arow = ap + (long long)(m0 + row_l) * 512;
      unsigned short* srow = S + row_l * 512;
#pragma unroll
      for (int c = 0; c < 32; ++c) {
        float p = acc[c][j] * inv[j];
        int col = c * 16 + l16;
        arow[col] = p;
        srow[((col >> 3) ^ rs) * 8 + (col & 7)] = f2b(p);
      }
    }
  }
  __syncthreads();                       // V half0 staged + S visible

  // ---- PV: ctx[16 rows][64 hd] per wave, K=512 in two halves ----
  const unsigned short* Vl = lds + 32768;
  f32x4 acc2[4];
#pragma unroll
  for (int c2 = 0; c2 < 4; ++c2) { f32x4 zz = {0.f, 0.f, 0.f, 0.f}; acc2[c2] = zz; }
  const int qrow = w * 16 + l16;
#pragma unroll
  for (int kk = 0; kk < 8; ++kk) {
    s16x8 a = *(const s16x8*)&S[qrow * 512 + ((kk * 4 + lhi) ^ rx7) * 8];
#pragma unroll
    for (int c2 = 0; c2 < 4; ++c2) {
      s16x8 bf = *(const s16x8*)&Vl[(c2 * 16 + l16) * 256 + ((kk * 4 + lhi) ^ rx7) * 8];
      acc2[c2] = __builtin_amdgcn_mfma_f32_16x16x32_bf16(a, bf, acc2[c2], 0, 0, 0);
    }
  }
  __syncthreads();                       // done reading V half0
#pragma unroll
  for (int p = 0; p < 8; ++p) {          // stage V half 1
    int t = p * 256 + tid;
    int row = t >> 5, c = t & 31;
    gload16(Vt + (long long)z * 32768 + row * 512 + 256 + (c ^ (row & 7)) * 8,
            &lds[32768 + t * 8]);
  }
  __syncthreads();
#pragma unroll
  for (int kk = 8; kk < 16; ++kk) {
    s16x8 a = *(const s16x8*)&S[qrow * 512 + ((kk * 4 + lhi) ^ rx7) * 8];
#pragma unroll
    for (int c2 = 0; c2 < 4; ++c2) {
      s16x8 bf = *(const s16x8*)&Vl[(c2 * 16 + l16) * 256 + (((kk - 8) * 4 + lhi) ^ rx7) * 8];
      acc2[c2] = __builtin_amdgcn_mfma_f32_16x16x32_bf16(a, bf, acc2[c2], 0, 0, 0);
    }
  }
  // ---- ctx store: (B,S,D) bf16 ----
#pragma unroll
  for (int c2 = 0; c2 < 4; ++c2) {
#pragma unroll
    for (int j = 0; j < 4; ++j) {
      int row_g = m0 + w * 16 + lhi * 4 + j;
      ctx[((long long)(b * 512 + row_g)) * 512 + h * 64 + c2 * 16 + l16] = f2b(acc2[c2][j]);
    }
  }
}

// ---------- weight transpose ----------
__global__ __launch_bounds__(256) void wt_k(Ptr6 srcs, unsigned short* __restrict__ wt) {
  __shared__ float tile[32][33];
  int zz = blockIdx.z;
  int l = zz / 6, mat = zz % 6;
  const float* src = srcs.p[mat] + (long long)l * 262144;
  int tx = threadIdx.x, ty = threadIdx.y;
  int n0 = blockIdx.x * 32, k0 = blockIdx.y * 32;
#pragma unroll
  for (int r = 0; r < 4; ++r)
    tile[ty + r * 8][tx] = src[(long long)(k0 + ty + r * 8) * 512 + n0 + tx];
  __syncthreads();
#pragma unroll
  for (int r = 0; r < 4; ++r)
    wt[(long long)zz * 262144 + (long long)(n0 + ty + r * 8) * 512 + k0 + tx] =
        f2b(tile[tx][ty + r * 8]);
}

// ---------- bias packing + fused quantum matrices ----------
__global__ __launch_bounds__(256) void prep_k(Ptr6 biases,
    const float* __restrict__ qwr, const float* __restrict__ qwi, const float* __restrict__ qem,
    const float* __restrict__ kwr, const float* __restrict__ kwi, const float* __restrict__ kem,
    float* __restrict__ biasPacked, float* __restrict__ ArAi) {
  int l = blockIdx.x, t = threadIdx.x;
  for (int m = 0; m < 6; ++m)
    for (int d = t; d < 512; d += 256)
      biasPacked[(l * 6 + m) * 512 + d] = biases.p[m][l * 512 + d];
  int i = t >> 4, j = t & 15;
  const float* em0 = qem + l * 256;
  float ar = 0.f, ai = 0.f;
  for (int tt = 0; tt < 16; ++tt) {
    ar += qwr[l * 256 + i * 16 + tt] * em0[tt * 16 + j];
    ai += qwi[l * 256 + i * 16 + tt] * em0[tt * 16 + j];
  }
  ArAi[(l * 4 + 0) * 256 + t] = ar;
  ArAi[(l * 4 + 1) * 256 + t] = ai;
  const float* em1 = kem + l * 256;
  ar = 0.f; ai = 0.f;
  for (int tt = 0; tt < 16; ++tt) {
    ar += kwr[l * 256 + i * 16 + tt] * em1[tt * 16 + j];
    ai += kwi[l * 256 + i * 16 + tt] * em1[tt * 16 + j];
  }
  ArAi[(l * 4 + 2) * 256 + t] = ar;
  ArAi[(l * 4 + 3) * 256 + t] = ai;
}

// ---------- visual projection ----------
__global__ __launch_bounds__(512) void vispart_k(const float* __restrict__ vis,
    const float* __restrict__ Wvis, float* __restrict__ part) {
  int b = blockIdx.x, chunk = blockIdx.y, d = threadIdx.x;
  float acc = 0.f;
  for (int k = chunk * 64; k < chunk * 64 + 64; ++k)
    acc += vis[b * 2048 + k] * Wvis[(long long)k * 512 + d];
  part[(b * 32 + chunk) * 512 + d] = acc;
}
__global__ __launch_bounds__(512) void projsum_k(const float* __restrict__ part,
    const float* __restrict__ bvis, const float* __restrict__ temporal,
    const float* __restrict__ Wtemp, const float* __restrict__ btemp, float* __restrict__ proj) {
  int b = blockIdx.x, d = threadIdx.x;
  float acc = bvis[d] + btemp[d];
  for (int c = 0; c < 32; ++c) acc += part[(b * 32 + c) * 512 + d];
  for (int k = 0; k < 64; ++k) acc += temporal[b * 64 + k] * Wtemp[k * 512 + d];
  proj[b * 512 + d] = acc;
}

// ---------- embedding + positional encoding ----------
__global__ __launch_bounds__(512) void embed_k(const int* __restrict__ text,
    const float* __restrict__ emb, const float* __restrict__ proj,
    float* __restrict__ x, unsigned short* __restrict__ xb) {
  int row = blockIdx.x;
  int b = row >> 9, s = row & 511;
  int d = threadIdx.x;
  int tok = text[row];
  float v = emb[(long long)tok * 512 + d] + proj[b * 512 + d];
  float fr = __expf((float)((d >> 1) << 1) * (-9.2103403719761836f / 512.f));
  float ang = (float)s * fr;
  v += (d & 1) ? cosf(ang) : sinf(ang);
  x[(long long)row * 512 + d] = v;
  xb[(long long)row * 512 + d] = f2b(v);
}

// ---------- quantum branch ----------
__global__ __launch_bounds__(64) void quantum_k(const float* __restrict__ x,
    const float* __restrict__ sg_q, const float* __restrict__ sg_k,
    const float* __restrict__ ArAiL, float* __restrict__ qp, float* __restrict__ kp,
    float* __restrict__ fwq, float* __restrict__ fwk) {
  int row = blockIdx.x, side = blockIdx.y, lane = threadIdx.x;
  const float* sg = side ? sg_k : sg_q;
  const float* Ar = ArAiL + side * 512;
  const float* Ai = Ar + 256;
  float acc[16];
#pragma unroll
  for (int j = 0; j < 16; ++j) acc[j] = 0.f;
  const float* xr = x + (long long)row * 512;
#pragma unroll
  for (int kk = 0; kk < 8; ++kk) {
    float xv = xr[kk * 64 + lane];
    const float* sgr = sg + (kk * 64 + lane) * 16;
#pragma unroll
    for (int j = 0; j < 16; ++j) acc[j] += xv * sgr[j];
  }
#pragma unroll
  for (int s = 32; s; s >>= 1)
#pragma unroll
    for (int j = 0; j < 16; ++j) acc[j] += __shfl_xor(acc[j], s);
  int j = lane & 15;
  float tr = 0.f, ti = 0.f;
#pragma unroll
  for (int t = 0; t < 16; ++t) {
    tr += acc[t] * Ar[t * 16 + j];
    ti += acc[t] * Ai[t * 16 + j];
  }
  float p = tr * tr + ti * ti;
  float ps = p;
#pragma unroll
  for (int s = 1; s < 16; s <<= 1) ps += __shfl_xor(ps, s);
  if (lane < 16) (side ? kp : qp)[row * 16 + lane] = p;
  if (lane == 0) (side ? fwk : fwq)[row] = 1.f / (1.f + __expf(-ps * (1.f / 16.f)));
}

// ---------- fuse (both sides in one launch) ----------
struct FuseP {
  const float* lin; const float* cl; const float* qp; const float* fw;
  const float* mb; unsigned short* ext; float sA, sB;
};
struct Fuse2 { FuseP s[2]; };
__global__ __launch_bounds__(512) void fuse_k(Fuse2 fp) {
  FuseP P = fp.s[blockIdx.y];
  int row = blockIdx.x;
  int b = row >> 9, i = row & 511;
  int d = threadIdx.x;
  const float* qpr = P.qp + row * 16;
  float fwv = P.fw[row];
  float qout = 0.f;
#pragma unroll
  for (int t = 0; t < 16; ++t) qout += qpr[t] * P.mb[t * 512 + d];
  float qq = fwv * qout + (1.f - fwv) * tanhf(P.cl[(long long)row * 512 + d]);
  float val = (0.7f * P.lin[(long long)row * 512 + d] + 0.3f * qq) * P.sA;
  int h = d >> 6, dd = d & 63;
  P.ext[(((long long)(b * 8 + h)) * 512 + i) * 96 + dd] = f2b(val);
  if (d < 128) {
    int h2 = d >> 4, j = d & 15;
    P.ext[(((long long)(b * 8 + h2)) * 512 + i) * 96 + 64 + j] = f2b(P.sB * qpr[j]);
  } else if (d < 256) {
    int t2 = d - 128;
    int h2 = t2 >> 4, j = t2 & 15;
    P.ext[(((long long)(b * 8 + h2)) * 512 + i) * 96 + 80 + j] = 0;
  }
}

// ---------- wave-per-row layernorm ----------
__global__ __launch_bounds__(256) void ln_k(const float* __restrict__ y,
    const float* __restrict__ g, const float* __restrict__ be,
    float* __restrict__ xo, unsigned short* __restrict__ xb, float* __restrict__ xo2) {
  int wv = threadIdx.x >> 6, lane = threadIdx.x & 63;
  long long row = (long long)blockIdx.x * 4 + wv;
  const float* yr = y + row * 512 + lane * 8;
  f32x4 a = *(const f32x4*)yr, b = *(const f32x4*)(yr + 4);
  float s = a[0] + a[1] + a[2] + a[3] + b[0] + b[1] + b[2] + b[3];
#pragma unroll
  for (int m = 32; m; m >>= 1) s += __shfl_xor(s, m);
  float mu = s * (1.f / 512.f);
  float d[8], vs = 0.f;
#pragma unroll
  for (int j = 0; j < 4; ++j) { d[j] = a[j] - mu; vs += d[j] * d[j]; }
#pragma unroll
  for (int j = 0; j < 4; ++j) { d[4 + j] = b[j] - mu; vs += d[4 + j] * d[4 + j]; }
#pragma unroll
  for (int m = 32; m; m >>= 1) vs += __shfl_xor(vs, m);
  float rstd = rsqrtf(vs * (1.f / 512.f) + 1e-5f);
  f32x4 g0 = *(const f32x4*)(g + lane * 8), g1 = *(const f32x4*)(g + lane * 8 + 4);
  f32x4 b0 = *(const f32x4*)(be + lane * 8), b1 = *(const f32x4*)(be + lane * 8 + 4);
  f32x4 o0, o1; s16x8 ob;
#pragma unroll
  for (int j = 0; j < 4; ++j) { o0[j] = d[j] * rstd * g0[j] + b0[j]; ob[j] = (short)f2b(o0[j]); }
#pragma unroll
  for (int j = 0; j < 4; ++j) { o1[j] = d[4 + j] * rstd * g1[j] + b1[j]; ob[4 + j] = (short)f2b(o1[j]); }
  float* xr = xo + row * 512 + lane * 8;
  *(f32x4*)xr = o0; *(f32x4*)(xr + 4) = o1;
  *(s16x8*)(xb + row * 512 + lane * 8) = ob;
  if (xo2) {
    float* x2 = xo2 + row * 512 + lane * 8;
    *(f32x4*)x2 = o0; *(f32x4*)(x2 + 4) = o1;
  }
}

// ---------- pooled heads (partial sums then final) ----------
__global__ __launch_bounds__(512) void poolpart_k(const float* __restrict__ x,
                                                   float* __restrict__ part) {
  int b = blockIdx.x, ch = blockIdx.y, d = threadIdx.x;
  float s = 0.f;
  for (int r = 0; r < 64; ++r) s += x[((long long)(b * 512 + ch * 64 + r)) * 512 + d];
  part[(b * 8 + ch) * 512 + d] = s;
}
__global__ __launch_bounds__(512) void head_k(const float* __restrict__ part,
    const float* __restrict__ Ws, const float* __restrict__ bs,
    const float* __restrict__ Wd, const float* __restrict__ bd,
    const float* __restrict__ We, const float* __restrict__ be, float* __restrict__ out) {
  __shared__ float pooled[512];
  __shared__ float dl[5];
  int b = blockIdx.x, d = threadIdx.x;
  float s = 0.f;
  for (int t = 0; t < 8; ++t) s += part[(b * 8 + t) * 512 + d];
  pooled[d] = s * (1.f / 512.f);
  __syncthreads();
  if (d < 64) {
    float a = bs[d];
    for (int t = 0; t < 512; ++t) a += pooled[t] * Ws[t * 64 + d];
    out[b * 64 + d] = 1.f / (1.f + __expf(-a));
  } else if (d < 69) {
    int j = d - 64;
    float a = bd[j];
    for (int t = 0; t < 512; ++t) a += pooled[t] * Wd[t * 5 + j];
    dl[j] = a;
  } else if (d == 69) {
    float a = be[0];
    for (int t = 0; t < 512; ++t) a += pooled[t] * We[t];
    out[276 + b] = 1.f / (1.f + __expf(-a));
  }
  __syncthreads();
  if (d < 5) {
    float mx = dl[0];
    for (int j = 1; j < 5; ++j) mx = fmaxf(mx, dl[j]);
    float sm = 0.f;
    for (int j = 0; j < 5; ++j) sm += __expf(dl[j] - mx);
    out[256 + b * 5 + d] = __expf(dl[d] - mx) / sm;
  }
}

// ---------- host ----------
extern "C" void kernel_launch(void* const* d_in, const int* in_sizes, int n_in,
                              void* d_out, int out_size, void* d_ws, size_t ws_size,
                              hipStream_t stream) {
  (void)in_sizes; (void)n_in; (void)out_size; (void)ws_size;
  const int*   text     = (const int*)  d_in[0];
  const float* visual   = (const float*)d_in[1];
  const float* temporal = (const float*)d_in[2];
  const float* embedw   = (const float*)d_in[3];
  const float* Wvis  = (const float*)d_in[4];  const float* bvis  = (const float*)d_in[5];
  const float* Wtemp = (const float*)d_in[6];  const float* btemp = (const float*)d_in[7];
  const float* Wq = (const float*)d_in[8];   const float* bq = (const float*)d_in[9];
  const float* Wk = (const float*)d_in[10];  const float* bk = (const float*)d_in[11];
  const float* Wv = (const float*)d_in[12];  const float* bv = (const float*)d_in[13];
  const float* Wo = (const float*)d_in[14];  const float* bo = (const float*)d_in[15];
  const float* qW = (const float*)d_in[16];  const float* qb = (const float*)d_in[17];
  const float* q_qwr = (const float*)d_in[18]; const float* q_qwi = (const float*)d_in[19];
  const float* q_sg  = (const float*)d_in[20]; const float* q_em  = (const float*)d_in[21];
  const float* q_mb  = (const float*)d_in[22];
  const float* kW = (const float*)d_in[23];  const float* kb = (const float*)d_in[24];
  const float* k_qwr = (const float*)d_in[25]; const float* k_qwi = (const float*)d_in[26];
  const float* k_sg  = (const float*)d_in[27]; const float* k_em  = (const float*)d_in[28];
  const float* k_mb  = (const float*)d_in[29];
  const float* ln_g = (const float*)d_in[30]; const float* ln_b = (const float*)d_in[31];
  const float* Ws = (const float*)d_in[32];  const float* bs_ = (const float*)d_in[33];
  const float* Wd = (const float*)d_in[34];  const float* bd = (const float*)d_in[35];
  const float* We = (const float*)d_in[36];  const float* be = (const float*)d_in[37];
  float* out = (float*)d_out;

  char* w = (char*)d_ws;
  auto alloc = [&](size_t bytes) {
    char* p = w;
    w += (bytes + 255) & ~(size_t)255;
    return p;
  };
  float* ws_x   = (float*)alloc(2048ll * 512 * 4);
  unsigned short* ws_xb = (unsigned short*)alloc(2048ll * 512 * 2);
  unsigned short* ws_Wt = (unsigned short*)alloc(36ll * 262144 * 2);
  float* ws_bias = (float*)alloc(6ll * 6 * 512 * 4);
  float* ws_ArAi = (float*)alloc(6ll * 1024 * 4);
  float* ws_proj = (float*)alloc(4ll * 512 * 4);
  float* ws_vp   = (float*)alloc(4ll * 32 * 512 * 4);
  float* ws_Q    = (float*)alloc(2048ll * 512 * 4);
  float* ws_K    = (float*)alloc(2048ll * 512 * 4);
  float* ws_Cq   = (float*)alloc(2048ll * 512 * 4);
  float* ws_Ck   = (float*)alloc(2048ll * 512 * 4);
  float* ws_qp   = (float*)alloc(2048ll * 16 * 4);
  float* ws_kp   = (float*)alloc(2048ll * 16 * 4);
  float* ws_fwq  = (float*)alloc(2048ll * 4);
  float* ws_fwk  = (float*)alloc(2048ll * 4);
  unsigned short* ws_Vt   = (unsigned short*)alloc(2048ll * 512 * 2);
  unsigned short* ws_Qext = (unsigned short*)alloc(4ll * 8 * 512 * 96 * 2);
  unsigned short* ws_Kext = (unsigned short*)alloc(4ll * 8 * 512 * 96 * 2);
  unsigned short* ws_ctx  = (unsigned short*)alloc(2048ll * 512 * 2);
  float* ws_y    = (float*)alloc(2048ll * 512 * 4);

  Ptr6 wsrc = {{Wq, Wk, Wv, qW, kW, Wo}};
  wt_k<<<dim3(16, 16, 36), dim3(32, 8), 0, stream>>>(wsrc, ws_Wt);
  Ptr6 bsrc = {{bq, bk, bv, qb, kb, bo}};
  prep_k<<<dim3(6), dim3(256), 0, stream>>>(bsrc, q_qwr, q_qwi, q_em, k_qwr, k_qwi, k_em,
                                            ws_bias, ws_ArAi);
  vispart_k<<<dim3(4, 32), dim3(512), 0, stream>>>(visual, Wvis, ws_vp);
  projsum_k<<<dim3(4), dim3(512), 0, stream>>>(ws_vp, bvis, temporal, Wtemp, btemp, ws_proj);
  embed_k<<<dim3(2048), dim3(512), 0, stream>>>(text, embedw, ws_proj, ws_x, ws_xb);

  const long long ATTN_OFF = 280ll + 1048576ll;
  for (int l = 0; l < 6; ++l) {
    const unsigned short* WtL = ws_Wt + (long long)l * 6 * 262144;
    const float* biasL = ws_bias + (long long)l * 6 * 512;

    Outs5 o5{};
    o5.o[0] = { ws_Q, MODE_F32 };  o5.o[1] = { ws_K, MODE_F32 };
    o5.o[2] = { ws_Vt, MODE_VT };  o5.o[3] = { ws_Cq, MODE_F32 };
    o5.o[4] = { ws_Ck, MODE_F32 };
    gemm_nt<128, 128, 2, 2><<<dim3(16, 4, 5), 256, 0, stream>>>(
        ws_xb, 512, 0ll, WtL, 512, 262144ll, biasL, 512, 1, o5, nullptr, 512);

    quantum_k<<<dim3(2048, 2), 64, 0, stream>>>(ws_x, q_sg + l * 8192, k_sg + l * 8192,
        ws_ArAi + l * 1024, ws_qp, ws_kp, ws_fwq, ws_fwk);

    Fuse2 f2{};
    f2.s[0] = { ws_Q, ws_Cq, ws_qp, ws_fwq, q_mb + l * 8192, ws_Qext, 0.125f, 0.1f };
    f2.s[1] = { ws_K, ws_Ck, ws_kp, ws_fwk, k_mb + l * 8192, ws_Kext, 1.0f, 1.0f };
    fuse_k<<<dim3(2048, 2), dim3(512), 0, stream>>>(f2);

    fused_attn<<<dim3(32, 8), 256, 0, stream>>>(
        ws_Qext, ws_Kext, ws_Vt, out + ATTN_OFF + (long long)l * 8388608, ws_ctx);

    Outs5 oy{};
    oy.o[0] = { ws_y, MODE_Y };
    gemm_nt<64, 64, 2, 2><<<dim3(32, 8, 1), 256, 0, stream>>>(
        ws_ctx, 512, 0ll, WtL + 5 * 262144, 512, 0ll, biasL + 5 * 512, 0, 0, oy, ws_x, 512);

    ln_k<<<dim3(512), dim3(256), 0, stream>>>(ws_y, ln_g + l * 512, ln_b + l * 512,
        ws_x, ws_xb, (l == 5) ? (out + 280) : nullptr);
  }

  poolpart_k<<<dim3(4, 8), dim3(512), 0, stream>>>(ws_x, ws_vp);
  head_k<<<dim3(4), dim3(512), 0, stream>>>(ws_vp, Ws, bs_, Wd, bd, We, be, out);
}